// Round 3
// baseline (530.333 us; speedup 1.0000x reference)
//
#include <hip/hip_runtime.h>

typedef unsigned short ushort_t;
typedef unsigned int uint_t;

typedef __bf16 bf16x8 __attribute__((ext_vector_type(8)));
typedef float f32x4 __attribute__((ext_vector_type(4)));

#define N_NODES 50000
#define N_EDGES 800000
#define DIM 128
#define NUM_GRAPHS 512
#define LDA 136  // padded LDS row stride in bf16 elems (128+8)

__device__ __forceinline__ float bf2f(ushort_t u) {
    return __uint_as_float(((uint_t)u) << 16);
}
__device__ __forceinline__ ushort_t f2bf(float f) {
    uint_t u = __float_as_uint(f);
    u = (u + 0x7FFF + ((u >> 16) & 1)) >> 16;  // RNE
    return (ushort_t)u;
}
__device__ __forceinline__ bf16x8 as_bf16x8(uint4 v) {
    return __builtin_bit_cast(bf16x8, v);
}

// ---------------- dtype detection ----------------
// flags[0] = 1 if float arrays are fp32 (else bf16)
// flags[1] = 1 if int arrays are int64 (else int32)
__global__ void detect_kernel(const void* xraw, const void* eiraw, int* flags) {
    if (threadIdx.x == 0 && blockIdx.x == 0) {
        const ushort_t* u = (const ushort_t*)xraw;
        int extreme = 0;
        for (int i = 0; i < 128; ++i) {
            int e = (u[i] >> 7) & 0xFF;
            if (e >= 0xC0) extreme++;  // |x| >= 2^65: impossible for bf16 N(0,1)
        }
        flags[0] = (extreme > 8) ? 1 : 0;
        const int* p = (const int*)eiraw;
        int nonzero = 0;
        for (int i = 1; i < 64; i += 2) nonzero += (p[i] != 0);
        flags[1] = (nonzero == 0) ? 1 : 0;  // all high-halves zero => int64
    }
}

// ---------------- canonicalization ----------------
__global__ void conv_x_kernel(const void* xraw, const int* __restrict__ flags,
                              ushort_t* __restrict__ out, int n) {
    int i = blockIdx.x * 256 + threadIdx.x;
    if (i >= n) return;
    out[i] = flags[0] ? f2bf(((const float*)xraw)[i]) : ((const ushort_t*)xraw)[i];
}

__global__ void conv_edges_kernel(const void* eiraw, const int* __restrict__ flags,
                                  int* __restrict__ src, int* __restrict__ dsto) {
    int e = blockIdx.x * 256 + threadIdx.x;
    if (e >= N_EDGES) return;
    const int* p = (const int*)eiraw;
    if (flags[1]) {  // int64: take low halves (little-endian)
        src[e] = p[2 * e];
        dsto[e] = p[2 * (N_EDGES + e)];
    } else {
        src[e] = p[e];
        dsto[e] = p[N_EDGES + e];
    }
}

__global__ void conv_batch_kernel(const void* braw, const int* __restrict__ flags,
                                  int* __restrict__ out) {
    int i = blockIdx.x * 256 + threadIdx.x;
    if (i >= N_NODES) return;
    const int* p = (const int*)braw;
    out[i] = flags[1] ? p[2 * i] : p[i];
}

// canonical fp32 params: [0:128)=b1a [128:256)=b1b [256:384)=b2a [384:512)=b2b
//                        [512:768)=Wfc(row-major 128x2) [768:770)=bfc
__global__ __launch_bounds__(1024) void conv_params_kernel(
    const void* pb1a, const void* pb1b, const void* pb2a, const void* pb2b,
    const void* pWfc, const void* pbfc, const int* __restrict__ flags,
    float* __restrict__ out) {
    int i = threadIdx.x;
    const void* srcp;
    int j;
    if (i < 128)      { srcp = pb1a; j = i; }
    else if (i < 256) { srcp = pb1b; j = i - 128; }
    else if (i < 384) { srcp = pb2a; j = i - 256; }
    else if (i < 512) { srcp = pb2b; j = i - 384; }
    else if (i < 768) { srcp = pWfc; j = i - 512; }
    else if (i < 770) { srcp = pbfc; j = i - 768; }
    else return;
    out[i] = flags[0] ? ((const float*)srcp)[j] : bf2f(((const ushort_t*)srcp)[j]);
}

// ---------------- CSR build (counting sort by dst) ----------------

__global__ void zero_int_kernel(int* p, int n) {
    int i = blockIdx.x * 256 + threadIdx.x;
    if (i < n) p[i] = 0;
}

__global__ void hist_kernel(const int* __restrict__ dst, int* __restrict__ cnt) {
    int e = blockIdx.x * 256 + threadIdx.x;
    if (e < N_EDGES) atomicAdd(&cnt[dst[e]], 1);
}

// cnt is consumed and rewritten in-place as the running cursor ("cur").
__global__ __launch_bounds__(1024) void scan_kernel(int* __restrict__ cnt,
                                                    int* __restrict__ rp) {
    __shared__ int buf[1024];
    __shared__ int carry_s;
    int t = threadIdx.x;
    if (t == 0) carry_s = 0;
    __syncthreads();
    for (int base = 0; base < N_NODES; base += 1024) {
        int v = (base + t < N_NODES) ? cnt[base + t] : 0;
        buf[t] = v;
        __syncthreads();
        for (int off = 1; off < 1024; off <<= 1) {
            int x = (t >= off) ? buf[t - off] : 0;
            __syncthreads();
            buf[t] += x;
            __syncthreads();
        }
        int incl = buf[t];
        int excl = incl - v;
        int c = carry_s;
        if (base + t < N_NODES) {
            rp[base + t] = c + excl;
            cnt[base + t] = c + excl;  // becomes "cur" for fill_kernel
        }
        __syncthreads();
        if (t == 1023) carry_s = c + incl;
        __syncthreads();
    }
    if (t == 0) rp[N_NODES] = carry_s;
}

__global__ void fill_kernel(const int* __restrict__ src, const int* __restrict__ dst,
                            int* __restrict__ cur, int* __restrict__ csr) {
    int e = blockIdx.x * 256 + threadIdx.x;
    if (e < N_EDGES) {
        int p = atomicAdd(&cur[dst[e]], 1);
        csr[p] = src[e];
    }
}

// ---------------- W -> B-fragment permutation ----------------
// B-frag for (kstep s, ntile t, lane L): 8 bf16 = W[k=s*32+(L>>4)*8+j][n=t*16+(L&15)]
__global__ void wperm_kernel(const void* Wraw, const int* __restrict__ flags,
                             ushort_t* __restrict__ out) {
    int idx = blockIdx.x * 256 + threadIdx.x;  // 0..16383
    int j = idx & 7;
    int L = (idx >> 3) & 63;
    int t = (idx >> 9) & 7;
    int s = idx >> 12;
    int k = s * 32 + (L >> 4) * 8 + j;
    int n = t * 16 + (L & 15);
    int off = k * DIM + n;
    out[idx] = flags[0] ? f2bf(((const float*)Wraw)[off]) : ((const ushort_t*)Wraw)[off];
}

// ---------------- aggregation: h[n] = feat[n] + sum_{j in in-edges} feat[src_j] ----
__global__ __launch_bounds__(256) void agg_kernel(const ushort_t* __restrict__ feat,
                                                  const int* __restrict__ rp,
                                                  const int* __restrict__ csr,
                                                  ushort_t* __restrict__ hout) {
    int n = blockIdx.x * 4 + (threadIdx.x >> 6);
    int lane = threadIdx.x & 63;
    if (n >= N_NODES) return;
    const uint_t* f32p = reinterpret_cast<const uint_t*>(feat);
    uint_t v = f32p[n * 64 + lane];
    float a0 = bf2f((ushort_t)(v & 0xffff));
    float a1 = bf2f((ushort_t)(v >> 16));
    int e0 = rp[n], e1 = rp[n + 1];
    for (int j = e0; j < e1; ++j) {
        int s = csr[j];
        uint_t w = f32p[s * 64 + lane];
        a0 += bf2f((ushort_t)(w & 0xffff));
        a1 += bf2f((ushort_t)(w >> 16));
    }
    uint_t o = (uint_t)f2bf(a0) | ((uint_t)f2bf(a1) << 16);
    reinterpret_cast<uint_t*>(hout)[n * 64 + lane] = o;
}

// ---------------- fused MLP: hout = relu(relu(hin@Wa+ba)@Wb+bb) ----------------
// 64 rows per 256-thread block (4 waves). Safe in-place (stages own rows first).
__global__ __launch_bounds__(256) void mlp_kernel(const ushort_t* __restrict__ hin,
                                                  const ushort_t* __restrict__ wpA,
                                                  const float* __restrict__ ba,
                                                  const ushort_t* __restrict__ wpB,
                                                  const float* __restrict__ bb,
                                                  ushort_t* __restrict__ hout) {
    __shared__ ushort_t As[64 * LDA];
    int tid = threadIdx.x;
    int wave = tid >> 6;
    int lane = tid & 63;
    int quad = lane >> 4;
    int cl = lane & 15;
    int row0 = blockIdx.x * 64;

    bf16x8 B1[2][4], B2[2][4];
#pragma unroll
    for (int ti = 0; ti < 2; ++ti) {
        int t = 2 * wave + ti;
#pragma unroll
        for (int s = 0; s < 4; ++s) {
            B1[ti][s] = as_bf16x8(reinterpret_cast<const uint4*>(wpA)[(s * 8 + t) * 64 + lane]);
            B2[ti][s] = as_bf16x8(reinterpret_cast<const uint4*>(wpB)[(s * 8 + t) * 64 + lane]);
        }
    }

    for (int i = tid; i < 64 * 16; i += 256) {
        int r = i >> 4, c8 = i & 15;
        uint4 v = make_uint4(0u, 0u, 0u, 0u);
        int gr = row0 + r;
        if (gr < N_NODES)
            v = reinterpret_cast<const uint4*>(hin + (size_t)gr * DIM)[c8];
        *reinterpret_cast<uint4*>(&As[r * LDA + c8 * 8]) = v;
    }
    __syncthreads();

    f32x4 acc[4][2];
#pragma unroll
    for (int m = 0; m < 4; ++m)
#pragma unroll
        for (int ti = 0; ti < 2; ++ti)
#pragma unroll
            for (int r = 0; r < 4; ++r) acc[m][ti][r] = 0.f;

#pragma unroll
    for (int s = 0; s < 4; ++s) {
#pragma unroll
        for (int m = 0; m < 4; ++m) {
            bf16x8 a = *reinterpret_cast<const bf16x8*>(&As[(m * 16 + cl) * LDA + s * 32 + quad * 8]);
#pragma unroll
            for (int ti = 0; ti < 2; ++ti)
                acc[m][ti] = __builtin_amdgcn_mfma_f32_16x16x32_bf16(a, B1[ti][s], acc[m][ti], 0, 0, 0);
        }
    }
    __syncthreads();

#pragma unroll
    for (int ti = 0; ti < 2; ++ti) {
        int col = 32 * wave + ti * 16 + cl;
        float bv = ba[col];
#pragma unroll
        for (int m = 0; m < 4; ++m)
#pragma unroll
            for (int r = 0; r < 4; ++r) {
                float v = acc[m][ti][r] + bv;
                As[(m * 16 + quad * 4 + r) * LDA + col] = f2bf(fmaxf(v, 0.f));
            }
    }
    __syncthreads();

#pragma unroll
    for (int m = 0; m < 4; ++m)
#pragma unroll
        for (int ti = 0; ti < 2; ++ti)
#pragma unroll
            for (int r = 0; r < 4; ++r) acc[m][ti][r] = 0.f;

#pragma unroll
    for (int s = 0; s < 4; ++s) {
#pragma unroll
        for (int m = 0; m < 4; ++m) {
            bf16x8 a = *reinterpret_cast<const bf16x8*>(&As[(m * 16 + cl) * LDA + s * 32 + quad * 8]);
#pragma unroll
            for (int ti = 0; ti < 2; ++ti)
                acc[m][ti] = __builtin_amdgcn_mfma_f32_16x16x32_bf16(a, B2[ti][s], acc[m][ti], 0, 0, 0);
        }
    }

#pragma unroll
    for (int ti = 0; ti < 2; ++ti) {
        int col = 32 * wave + ti * 16 + cl;
        float bv = bb[col];
#pragma unroll
        for (int m = 0; m < 4; ++m)
#pragma unroll
            for (int r = 0; r < 4; ++r) {
                int gr = row0 + m * 16 + quad * 4 + r;
                if (gr < N_NODES) {
                    float v = acc[m][ti][r] + bv;
                    hout[(size_t)gr * DIM + col] = f2bf(fmaxf(v, 0.f));
                }
            }
    }
}

// ---------------- mean-pool per graph + FC(128->2) ----------------
__global__ __launch_bounds__(128) void pool_fc_kernel(const ushort_t* __restrict__ h2,
                                                      const int* __restrict__ batch,
                                                      const float* __restrict__ params,
                                                      const int* __restrict__ flags,
                                                      void* __restrict__ out) {
    int g = blockIdx.x;
    int d = threadIdx.x;
    int lo = 0, hi = N_NODES;
    while (lo < hi) { int mid = (lo + hi) >> 1; if (batch[mid] < g) lo = mid + 1; else hi = mid; }
    int start = lo;
    hi = N_NODES;
    while (lo < hi) { int mid = (lo + hi) >> 1; if (batch[mid] < g + 1) lo = mid + 1; else hi = mid; }
    int end = lo;

    float sum = 0.f;
    for (int n = start; n < end; ++n) sum += bf2f(h2[(size_t)n * DIM + d]);
    int c = end - start;
    float mean = sum / (float)(c > 0 ? c : 1);
    float p0 = mean * params[512 + d * 2 + 0];
    float p1 = mean * params[512 + d * 2 + 1];

    __shared__ float r0[128], r1[128];
    r0[d] = p0; r1[d] = p1;
    __syncthreads();
    for (int off = 64; off > 0; off >>= 1) {
        if (d < off) { r0[d] += r0[d + off]; r1[d] += r1[d + off]; }
        __syncthreads();
    }
    if (d == 0) {
        float o0 = r0[0] + params[768];
        float o1 = r1[0] + params[769];
        if (flags[0]) {  // fp32 problem -> fp32 output
            ((float*)out)[g * 2 + 0] = o0;
            ((float*)out)[g * 2 + 1] = o1;
        } else {         // bf16 problem -> bf16 output
            ((ushort_t*)out)[g * 2 + 0] = f2bf(o0);
            ((ushort_t*)out)[g * 2 + 1] = f2bf(o1);
        }
    }
}

extern "C" void kernel_launch(void* const* d_in, const int* in_sizes, int n_in,
                              void* d_out, int out_size, void* d_ws, size_t ws_size,
                              hipStream_t stream) {
    const void* x = d_in[0];
    const void* ei = d_in[1];
    const void* batch = d_in[2];
    const void* W1a = d_in[3];
    const void* b1a = d_in[4];
    const void* W1b = d_in[5];
    const void* b1b = d_in[6];
    const void* W2a = d_in[7];
    const void* b2a = d_in[8];
    const void* W2b = d_in[9];
    const void* b2b = d_in[10];
    const void* Wfc = d_in[11];
    const void* bfc = d_in[12];

    // Workspace layout (~36 MB, all chunks 16B-aligned)
    char* base = (char*)d_ws;
    ushort_t* hX = (ushort_t*)base;   base += (size_t)N_NODES * DIM * 2;   // 12.8 MB (also h2)
    ushort_t* hA = (ushort_t*)base;   base += (size_t)N_NODES * DIM * 2;   // 12.8 MB
    int* src32 = (int*)base;          base += (size_t)N_EDGES * 4;         // 3.2 MB
    int* dst32 = (int*)base;          base += (size_t)N_EDGES * 4;         // 3.2 MB
    int* batch32 = (int*)base;        base += (size_t)N_NODES * 4;         // 0.2 MB
    int* rp = (int*)base;             base += (size_t)(N_NODES + 4) * 4;
    int* cnt = (int*)base;            base += (size_t)N_NODES * 4;
    int* csr = (int*)base;            base += (size_t)N_EDGES * 4;         // 3.2 MB
    ushort_t* wpA1 = (ushort_t*)base; base += 16384 * 2;
    ushort_t* wpB1 = (ushort_t*)base; base += 16384 * 2;
    ushort_t* wpA2 = (ushort_t*)base; base += 16384 * 2;
    ushort_t* wpB2 = (ushort_t*)base; base += 16384 * 2;
    float* params = (float*)base;     base += 772 * 4;
    int* flags = (int*)base;          base += 16;

    // Detect dtypes, canonicalize
    detect_kernel<<<1, 64, 0, stream>>>(x, ei, flags);
    conv_x_kernel<<<(N_NODES * DIM + 255) / 256, 256, 0, stream>>>(x, flags, hX, N_NODES * DIM);
    conv_edges_kernel<<<(N_EDGES + 255) / 256, 256, 0, stream>>>(ei, flags, src32, dst32);
    conv_batch_kernel<<<(N_NODES + 255) / 256, 256, 0, stream>>>(batch, flags, batch32);
    conv_params_kernel<<<1, 1024, 0, stream>>>(b1a, b1b, b2a, b2b, Wfc, bfc, flags, params);
    wperm_kernel<<<64, 256, 0, stream>>>(W1a, flags, wpA1);
    wperm_kernel<<<64, 256, 0, stream>>>(W1b, flags, wpB1);
    wperm_kernel<<<64, 256, 0, stream>>>(W2a, flags, wpA2);
    wperm_kernel<<<64, 256, 0, stream>>>(W2b, flags, wpB2);

    // CSR build
    zero_int_kernel<<<(N_NODES + 255) / 256, 256, 0, stream>>>(cnt, N_NODES);
    hist_kernel<<<(N_EDGES + 255) / 256, 256, 0, stream>>>(dst32, cnt);
    scan_kernel<<<1, 1024, 0, stream>>>(cnt, rp);
    fill_kernel<<<(N_EDGES + 255) / 256, 256, 0, stream>>>(src32, dst32, cnt, csr);

    // Layer 1: agg(hX)->hA, mlp in-place on hA
    agg_kernel<<<(N_NODES + 3) / 4, 256, 0, stream>>>(hX, rp, csr, hA);
    mlp_kernel<<<(N_NODES + 63) / 64, 256, 0, stream>>>(hA, wpA1, params + 0, wpB1, params + 128, hA);
    // Layer 2: agg(hA)->hX, mlp in-place on hX
    agg_kernel<<<(N_NODES + 3) / 4, 256, 0, stream>>>(hA, rp, csr, hX);
    mlp_kernel<<<(N_NODES + 63) / 64, 256, 0, stream>>>(hX, wpA2, params + 256, wpB2, params + 384, hX);
    // Pool + FC
    pool_fc_kernel<<<NUM_GRAPHS, 128, 0, stream>>>(hX, batch32, params, flags, d_out);
}

// Round 4
// 446.240 us; speedup vs baseline: 1.1884x; 1.1884x over previous
//
#include <hip/hip_runtime.h>

typedef unsigned short ushort_t;
typedef unsigned int uint_t;

typedef __bf16 bf16x8 __attribute__((ext_vector_type(8)));
typedef float f32x4 __attribute__((ext_vector_type(4)));

#define N_NODES 50000
#define N_EDGES 800000
#define DIM 128
#define NUM_GRAPHS 512
#define LDA 136  // padded LDS row stride in bf16 elems (128+8)
#define SCAN_BLOCKS ((N_NODES + 255) / 256)  // 196

__device__ __forceinline__ float bf2f(ushort_t u) {
    return __uint_as_float(((uint_t)u) << 16);
}
__device__ __forceinline__ ushort_t f2bf(float f) {
    uint_t u = __float_as_uint(f);
    u = (u + 0x7FFF + ((u >> 16) & 1)) >> 16;  // RNE
    return (ushort_t)u;
}
__device__ __forceinline__ bf16x8 as_bf16x8(uint4 v) {
    return __builtin_bit_cast(bf16x8, v);
}

// ---------------- dtype detection ----------------
// flags[0] = 1 if float arrays are fp32 (else bf16)
// flags[1] = 1 if int arrays are int64 (else int32)
__global__ void detect_kernel(const void* xraw, const void* eiraw, int* flags) {
    if (threadIdx.x == 0 && blockIdx.x == 0) {
        const ushort_t* u = (const ushort_t*)xraw;
        int extreme = 0;
        for (int i = 0; i < 128; ++i) {
            int e = (u[i] >> 7) & 0xFF;
            if (e >= 0xC0) extreme++;  // |x| >= 2^65: impossible for bf16 N(0,1)
        }
        flags[0] = (extreme > 8) ? 1 : 0;
        const int* p = (const int*)eiraw;
        int nonzero = 0;
        for (int i = 1; i < 64; i += 2) nonzero += (p[i] != 0);
        flags[1] = (nonzero == 0) ? 1 : 0;  // all high-halves zero => int64
    }
}

// ---------------- canonicalization ----------------
__global__ void conv_x_kernel(const void* xraw, const int* __restrict__ flags,
                              ushort_t* __restrict__ out, int n) {
    int i = blockIdx.x * 256 + threadIdx.x;
    if (i >= n) return;
    out[i] = flags[0] ? f2bf(((const float*)xraw)[i]) : ((const ushort_t*)xraw)[i];
}

__global__ void conv_edges_kernel(const void* eiraw, const int* __restrict__ flags,
                                  int* __restrict__ src, int* __restrict__ dsto) {
    int e = blockIdx.x * 256 + threadIdx.x;
    if (e >= N_EDGES) return;
    const int* p = (const int*)eiraw;
    if (flags[1]) {  // int64: take low halves (little-endian)
        src[e] = p[2 * e];
        dsto[e] = p[2 * (N_EDGES + e)];
    } else {
        src[e] = p[e];
        dsto[e] = p[N_EDGES + e];
    }
}

__global__ void conv_batch_kernel(const void* braw, const int* __restrict__ flags,
                                  int* __restrict__ out) {
    int i = blockIdx.x * 256 + threadIdx.x;
    if (i >= N_NODES) return;
    const int* p = (const int*)braw;
    out[i] = flags[1] ? p[2 * i] : p[i];
}

// canonical fp32 params: [0:128)=b1a [128:256)=b1b [256:384)=b2a [384:512)=b2b
//                        [512:768)=Wfc(row-major 128x2) [768:770)=bfc
__global__ __launch_bounds__(1024) void conv_params_kernel(
    const void* pb1a, const void* pb1b, const void* pb2a, const void* pb2b,
    const void* pWfc, const void* pbfc, const int* __restrict__ flags,
    float* __restrict__ out) {
    int i = threadIdx.x;
    const void* srcp;
    int j;
    if (i < 128)      { srcp = pb1a; j = i; }
    else if (i < 256) { srcp = pb1b; j = i - 128; }
    else if (i < 384) { srcp = pb2a; j = i - 256; }
    else if (i < 512) { srcp = pb2b; j = i - 384; }
    else if (i < 768) { srcp = pWfc; j = i - 512; }
    else if (i < 770) { srcp = pbfc; j = i - 768; }
    else return;
    out[i] = flags[0] ? ((const float*)srcp)[j] : bf2f(((const ushort_t*)srcp)[j]);
}

// ---------------- CSR build (counting sort by dst) ----------------

__global__ void zero_int_kernel(int* p, int n) {
    int i = blockIdx.x * 256 + threadIdx.x;
    if (i < n) p[i] = 0;
}

__global__ void hist_kernel(const int* __restrict__ dst, int* __restrict__ cnt) {
    int e = blockIdx.x * 256 + threadIdx.x;
    if (e < N_EDGES) atomicAdd(&cnt[dst[e]], 1);
}

// Two-level scan, stage 1: per-block (256-elem) sums.
__global__ __launch_bounds__(256) void scan_reduce_kernel(const int* __restrict__ cnt,
                                                          int* __restrict__ bsum) {
    __shared__ int buf[256];
    int t = threadIdx.x;
    int i = blockIdx.x * 256 + t;
    buf[t] = (i < N_NODES) ? cnt[i] : 0;
    __syncthreads();
    for (int off = 128; off > 0; off >>= 1) {
        if (t < off) buf[t] += buf[t + off];
        __syncthreads();
    }
    if (t == 0) bsum[blockIdx.x] = buf[0];
}

// Stage 2: single small block scans the SCAN_BLOCKS block sums (exclusive).
__global__ __launch_bounds__(256) void scan_bsum_kernel(int* __restrict__ bsum,
                                                        int* __restrict__ rp) {
    __shared__ int buf[256];
    int t = threadIdx.x;
    int v = (t < SCAN_BLOCKS) ? bsum[t] : 0;
    buf[t] = v;
    __syncthreads();
    for (int off = 1; off < 256; off <<= 1) {
        int x = (t >= off) ? buf[t - off] : 0;
        __syncthreads();
        buf[t] += x;
        __syncthreads();
    }
    if (t < SCAN_BLOCKS) bsum[t] = buf[t] - v;  // exclusive
    if (t == 255) rp[N_NODES] = buf[255];       // total edge count
}

// Stage 3: per-block exclusive rescan + block offset; writes rp and rewrites
// cnt in-place as the running cursor ("cur") for fill_kernel.
__global__ __launch_bounds__(256) void scan_final_kernel(int* __restrict__ cnt,
                                                         const int* __restrict__ bsum,
                                                         int* __restrict__ rp) {
    __shared__ int buf[256];
    int t = threadIdx.x;
    int i = blockIdx.x * 256 + t;
    int v = (i < N_NODES) ? cnt[i] : 0;
    buf[t] = v;
    __syncthreads();
    for (int off = 1; off < 256; off <<= 1) {
        int x = (t >= off) ? buf[t - off] : 0;
        __syncthreads();
        buf[t] += x;
        __syncthreads();
    }
    if (i < N_NODES) {
        int r = bsum[blockIdx.x] + buf[t] - v;  // exclusive prefix
        rp[i] = r;
        cnt[i] = r;
    }
}

__global__ void fill_kernel(const int* __restrict__ src, const int* __restrict__ dst,
                            int* __restrict__ cur, int* __restrict__ csr) {
    int e = blockIdx.x * 256 + threadIdx.x;
    if (e < N_EDGES) {
        int p = atomicAdd(&cur[dst[e]], 1);
        csr[p] = src[e];
    }
}

// ---------------- W -> B-fragment permutation ----------------
// B-frag for (kstep s, ntile t, lane L): 8 bf16 = W[k=s*32+(L>>4)*8+j][n=t*16+(L&15)]
__global__ void wperm_kernel(const void* Wraw, const int* __restrict__ flags,
                             ushort_t* __restrict__ out) {
    int idx = blockIdx.x * 256 + threadIdx.x;  // 0..16383
    int j = idx & 7;
    int L = (idx >> 3) & 63;
    int t = (idx >> 9) & 7;
    int s = idx >> 12;
    int k = s * 32 + (L >> 4) * 8 + j;
    int n = t * 16 + (L & 15);
    int off = k * DIM + n;
    out[idx] = flags[0] ? f2bf(((const float*)Wraw)[off]) : ((const ushort_t*)Wraw)[off];
}

// ---------------- aggregation: h[n] = feat[n] + sum_{j in in-edges} feat[src_j] ----
__global__ __launch_bounds__(256) void agg_kernel(const ushort_t* __restrict__ feat,
                                                  const int* __restrict__ rp,
                                                  const int* __restrict__ csr,
                                                  ushort_t* __restrict__ hout) {
    int n = blockIdx.x * 4 + (threadIdx.x >> 6);
    int lane = threadIdx.x & 63;
    if (n >= N_NODES) return;
    const uint_t* f32p = reinterpret_cast<const uint_t*>(feat);
    uint_t v = f32p[n * 64 + lane];
    float a0 = bf2f((ushort_t)(v & 0xffff));
    float a1 = bf2f((ushort_t)(v >> 16));
    int e0 = rp[n], e1 = rp[n + 1];
    for (int j = e0; j < e1; ++j) {
        int s = csr[j];
        uint_t w = f32p[s * 64 + lane];
        a0 += bf2f((ushort_t)(w & 0xffff));
        a1 += bf2f((ushort_t)(w >> 16));
    }
    uint_t o = (uint_t)f2bf(a0) | ((uint_t)f2bf(a1) << 16);
    reinterpret_cast<uint_t*>(hout)[n * 64 + lane] = o;
}

// ---------------- fused MLP: hout = relu(relu(hin@Wa+ba)@Wb+bb) ----------------
// 64 rows per 256-thread block (4 waves). Safe in-place (stages own rows first).
__global__ __launch_bounds__(256) void mlp_kernel(const ushort_t* __restrict__ hin,
                                                  const ushort_t* __restrict__ wpA,
                                                  const float* __restrict__ ba,
                                                  const ushort_t* __restrict__ wpB,
                                                  const float* __restrict__ bb,
                                                  ushort_t* __restrict__ hout) {
    __shared__ ushort_t As[64 * LDA];
    int tid = threadIdx.x;
    int wave = tid >> 6;
    int lane = tid & 63;
    int quad = lane >> 4;
    int cl = lane & 15;
    int row0 = blockIdx.x * 64;

    bf16x8 B1[2][4], B2[2][4];
#pragma unroll
    for (int ti = 0; ti < 2; ++ti) {
        int t = 2 * wave + ti;
#pragma unroll
        for (int s = 0; s < 4; ++s) {
            B1[ti][s] = as_bf16x8(reinterpret_cast<const uint4*>(wpA)[(s * 8 + t) * 64 + lane]);
            B2[ti][s] = as_bf16x8(reinterpret_cast<const uint4*>(wpB)[(s * 8 + t) * 64 + lane]);
        }
    }

    for (int i = tid; i < 64 * 16; i += 256) {
        int r = i >> 4, c8 = i & 15;
        uint4 v = make_uint4(0u, 0u, 0u, 0u);
        int gr = row0 + r;
        if (gr < N_NODES)
            v = reinterpret_cast<const uint4*>(hin + (size_t)gr * DIM)[c8];
        *reinterpret_cast<uint4*>(&As[r * LDA + c8 * 8]) = v;
    }
    __syncthreads();

    f32x4 acc[4][2];
#pragma unroll
    for (int m = 0; m < 4; ++m)
#pragma unroll
        for (int ti = 0; ti < 2; ++ti)
#pragma unroll
            for (int r = 0; r < 4; ++r) acc[m][ti][r] = 0.f;

#pragma unroll
    for (int s = 0; s < 4; ++s) {
#pragma unroll
        for (int m = 0; m < 4; ++m) {
            bf16x8 a = *reinterpret_cast<const bf16x8*>(&As[(m * 16 + cl) * LDA + s * 32 + quad * 8]);
#pragma unroll
            for (int ti = 0; ti < 2; ++ti)
                acc[m][ti] = __builtin_amdgcn_mfma_f32_16x16x32_bf16(a, B1[ti][s], acc[m][ti], 0, 0, 0);
        }
    }
    __syncthreads();

#pragma unroll
    for (int ti = 0; ti < 2; ++ti) {
        int col = 32 * wave + ti * 16 + cl;
        float bv = ba[col];
#pragma unroll
        for (int m = 0; m < 4; ++m)
#pragma unroll
            for (int r = 0; r < 4; ++r) {
                float v = acc[m][ti][r] + bv;
                As[(m * 16 + quad * 4 + r) * LDA + col] = f2bf(fmaxf(v, 0.f));
            }
    }
    __syncthreads();

#pragma unroll
    for (int m = 0; m < 4; ++m)
#pragma unroll
        for (int ti = 0; ti < 2; ++ti)
#pragma unroll
            for (int r = 0; r < 4; ++r) acc[m][ti][r] = 0.f;

#pragma unroll
    for (int s = 0; s < 4; ++s) {
#pragma unroll
        for (int m = 0; m < 4; ++m) {
            bf16x8 a = *reinterpret_cast<const bf16x8*>(&As[(m * 16 + cl) * LDA + s * 32 + quad * 8]);
#pragma unroll
            for (int ti = 0; ti < 2; ++ti)
                acc[m][ti] = __builtin_amdgcn_mfma_f32_16x16x32_bf16(a, B2[ti][s], acc[m][ti], 0, 0, 0);
        }
    }

#pragma unroll
    for (int ti = 0; ti < 2; ++ti) {
        int col = 32 * wave + ti * 16 + cl;
        float bv = bb[col];
#pragma unroll
        for (int m = 0; m < 4; ++m)
#pragma unroll
            for (int r = 0; r < 4; ++r) {
                int gr = row0 + m * 16 + quad * 4 + r;
                if (gr < N_NODES) {
                    float v = acc[m][ti][r] + bv;
                    hout[(size_t)gr * DIM + col] = f2bf(fmaxf(v, 0.f));
                }
            }
    }
}

// ---------------- mean-pool per graph + FC(128->2) ----------------
__global__ __launch_bounds__(128) void pool_fc_kernel(const ushort_t* __restrict__ h2,
                                                      const int* __restrict__ batch,
                                                      const float* __restrict__ params,
                                                      const int* __restrict__ flags,
                                                      void* __restrict__ out) {
    int g = blockIdx.x;
    int d = threadIdx.x;
    int lo = 0, hi = N_NODES;
    while (lo < hi) { int mid = (lo + hi) >> 1; if (batch[mid] < g) lo = mid + 1; else hi = mid; }
    int start = lo;
    hi = N_NODES;
    while (lo < hi) { int mid = (lo + hi) >> 1; if (batch[mid] < g + 1) lo = mid + 1; else hi = mid; }
    int end = lo;

    float sum = 0.f;
    for (int n = start; n < end; ++n) sum += bf2f(h2[(size_t)n * DIM + d]);
    int c = end - start;
    float mean = sum / (float)(c > 0 ? c : 1);
    float p0 = mean * params[512 + d * 2 + 0];
    float p1 = mean * params[512 + d * 2 + 1];

    __shared__ float r0[128], r1[128];
    r0[d] = p0; r1[d] = p1;
    __syncthreads();
    for (int off = 64; off > 0; off >>= 1) {
        if (d < off) { r0[d] += r0[d + off]; r1[d] += r1[d + off]; }
        __syncthreads();
    }
    if (d == 0) {
        float o0 = r0[0] + params[768];
        float o1 = r1[0] + params[769];
        if (flags[0]) {  // fp32 problem -> fp32 output
            ((float*)out)[g * 2 + 0] = o0;
            ((float*)out)[g * 2 + 1] = o1;
        } else {         // bf16 problem -> bf16 output
            ((ushort_t*)out)[g * 2 + 0] = f2bf(o0);
            ((ushort_t*)out)[g * 2 + 1] = f2bf(o1);
        }
    }
}

extern "C" void kernel_launch(void* const* d_in, const int* in_sizes, int n_in,
                              void* d_out, int out_size, void* d_ws, size_t ws_size,
                              hipStream_t stream) {
    const void* x = d_in[0];
    const void* ei = d_in[1];
    const void* batch = d_in[2];
    const void* W1a = d_in[3];
    const void* b1a = d_in[4];
    const void* W1b = d_in[5];
    const void* b1b = d_in[6];
    const void* W2a = d_in[7];
    const void* b2a = d_in[8];
    const void* W2b = d_in[9];
    const void* b2b = d_in[10];
    const void* Wfc = d_in[11];
    const void* bfc = d_in[12];

    // Workspace layout (~36 MB, all chunks 16B-aligned)
    char* base = (char*)d_ws;
    ushort_t* hX = (ushort_t*)base;   base += (size_t)N_NODES * DIM * 2;   // 12.8 MB (also h2)
    ushort_t* hA = (ushort_t*)base;   base += (size_t)N_NODES * DIM * 2;   // 12.8 MB
    int* src32 = (int*)base;          base += (size_t)N_EDGES * 4;         // 3.2 MB
    int* dst32 = (int*)base;          base += (size_t)N_EDGES * 4;         // 3.2 MB
    int* batch32 = (int*)base;        base += (size_t)N_NODES * 4;         // 0.2 MB
    int* rp = (int*)base;             base += (size_t)(N_NODES + 4) * 4;
    int* cnt = (int*)base;            base += (size_t)N_NODES * 4;
    int* bsum = (int*)base;           base += 256 * 4;
    int* csr = (int*)base;            base += (size_t)N_EDGES * 4;         // 3.2 MB
    ushort_t* wpA1 = (ushort_t*)base; base += 16384 * 2;
    ushort_t* wpB1 = (ushort_t*)base; base += 16384 * 2;
    ushort_t* wpA2 = (ushort_t*)base; base += 16384 * 2;
    ushort_t* wpB2 = (ushort_t*)base; base += 16384 * 2;
    float* params = (float*)base;     base += 772 * 4;
    int* flags = (int*)base;          base += 16;

    // Detect dtypes, canonicalize
    detect_kernel<<<1, 64, 0, stream>>>(x, ei, flags);
    conv_x_kernel<<<(N_NODES * DIM + 255) / 256, 256, 0, stream>>>(x, flags, hX, N_NODES * DIM);
    conv_edges_kernel<<<(N_EDGES + 255) / 256, 256, 0, stream>>>(ei, flags, src32, dst32);
    conv_batch_kernel<<<(N_NODES + 255) / 256, 256, 0, stream>>>(batch, flags, batch32);
    conv_params_kernel<<<1, 1024, 0, stream>>>(b1a, b1b, b2a, b2b, Wfc, bfc, flags, params);
    wperm_kernel<<<64, 256, 0, stream>>>(W1a, flags, wpA1);
    wperm_kernel<<<64, 256, 0, stream>>>(W1b, flags, wpB1);
    wperm_kernel<<<64, 256, 0, stream>>>(W2a, flags, wpA2);
    wperm_kernel<<<64, 256, 0, stream>>>(W2b, flags, wpB2);

    // CSR build (two-level scan replaces the 92 µs single-block scan)
    zero_int_kernel<<<(N_NODES + 255) / 256, 256, 0, stream>>>(cnt, N_NODES);
    hist_kernel<<<(N_EDGES + 255) / 256, 256, 0, stream>>>(dst32, cnt);
    scan_reduce_kernel<<<SCAN_BLOCKS, 256, 0, stream>>>(cnt, bsum);
    scan_bsum_kernel<<<1, 256, 0, stream>>>(bsum, rp);
    scan_final_kernel<<<SCAN_BLOCKS, 256, 0, stream>>>(cnt, bsum, rp);
    fill_kernel<<<(N_EDGES + 255) / 256, 256, 0, stream>>>(src32, dst32, cnt, csr);

    // Layer 1: agg(hX)->hA, mlp in-place on hA
    agg_kernel<<<(N_NODES + 3) / 4, 256, 0, stream>>>(hX, rp, csr, hA);
    mlp_kernel<<<(N_NODES + 63) / 64, 256, 0, stream>>>(hA, wpA1, params + 0, wpB1, params + 128, hA);
    // Layer 2: agg(hA)->hX, mlp in-place on hX
    agg_kernel<<<(N_NODES + 3) / 4, 256, 0, stream>>>(hA, rp, csr, hX);
    mlp_kernel<<<(N_NODES + 63) / 64, 256, 0, stream>>>(hX, wpA2, params + 256, wpB2, params + 384, hX);
    // Pool + FC
    pool_fc_kernel<<<NUM_GRAPHS, 128, 0, stream>>>(hX, batch32, params, flags, d_out);
}

// Round 5
// 334.404 us; speedup vs baseline: 1.5859x; 1.3344x over previous
//
#include <hip/hip_runtime.h>

typedef unsigned short ushort_t;
typedef unsigned int uint_t;

typedef __bf16 bf16x8 __attribute__((ext_vector_type(8)));
typedef float f32x4 __attribute__((ext_vector_type(4)));

#define N_NODES 50000
#define N_EDGES 800000
#define DIM 128
#define NUM_GRAPHS 512
#define LDA 136  // padded LDS row stride in bf16 elems (128+8)
#define SCAN_BLOCKS ((N_NODES + 255) / 256)  // 196

__device__ __forceinline__ float bf2f(ushort_t u) {
    return __uint_as_float(((uint_t)u) << 16);
}
__device__ __forceinline__ ushort_t f2bf(float f) {
    uint_t u = __float_as_uint(f);
    u = (u + 0x7FFF + ((u >> 16) & 1)) >> 16;  // RNE
    return (ushort_t)u;
}
__device__ __forceinline__ bf16x8 as_bf16x8(uint4 v) {
    return __builtin_bit_cast(bf16x8, v);
}

// ---------------- dtype detection ----------------
// flags[0] = 1 if float arrays are fp32 (else bf16)
// flags[1] = 1 if int arrays are int64 (else int32)
__global__ void detect_kernel(const void* xraw, const void* eiraw, int* flags) {
    if (threadIdx.x == 0 && blockIdx.x == 0) {
        const ushort_t* u = (const ushort_t*)xraw;
        int extreme = 0;
        for (int i = 0; i < 128; ++i) {
            int e = (u[i] >> 7) & 0xFF;
            if (e >= 0xC0) extreme++;  // |x| >= 2^65: impossible for bf16 N(0,1)
        }
        flags[0] = (extreme > 8) ? 1 : 0;
        const int* p = (const int*)eiraw;
        int nonzero = 0;
        for (int i = 1; i < 64; i += 2) nonzero += (p[i] != 0);
        flags[1] = (nonzero == 0) ? 1 : 0;  // all high-halves zero => int64
    }
}

// ---------------- canonicalization ----------------
// 4 elements per thread (float4 -> ushort4, or uint2 passthrough for bf16)
__global__ void conv_x_kernel(const void* xraw, const int* __restrict__ flags,
                              ushort_t* __restrict__ out) {
    int i = blockIdx.x * 256 + threadIdx.x;
    if (i >= N_NODES * DIM / 4) return;
    if (flags[0]) {
        float4 v = ((const float4*)xraw)[i];
        ushort4 o;
        o.x = f2bf(v.x); o.y = f2bf(v.y); o.z = f2bf(v.z); o.w = f2bf(v.w);
        ((ushort4*)out)[i] = o;
    } else {
        ((uint2*)out)[i] = ((const uint2*)xraw)[i];
    }
}

// edges -> int32 src/dst + histogram of dst (cnt must be pre-zeroed)
__global__ void conv_edges_hist_kernel(const void* eiraw, const int* __restrict__ flags,
                                       int* __restrict__ src, int* __restrict__ dsto,
                                       int* __restrict__ cnt) {
    int e = blockIdx.x * 256 + threadIdx.x;
    if (e >= N_EDGES) return;
    const int* p = (const int*)eiraw;
    int s, d;
    if (flags[1]) {  // int64: take low halves (little-endian)
        s = p[2 * e];
        d = p[2 * (N_EDGES + e)];
    } else {
        s = p[e];
        d = p[N_EDGES + e];
    }
    src[e] = s;
    dsto[e] = d;
    atomicAdd(&cnt[d], 1);
}

// blocks 0..48: batch -> int32.  block 49: params.
// canonical fp32 params: [0:128)=b1a [128:256)=b1b [256:384)=b2a [384:512)=b2b
//                        [512:768)=Wfc(row-major 128x2) [768:770)=bfc
__global__ __launch_bounds__(1024) void conv_batch_params_kernel(
    const void* braw,
    const void* pb1a, const void* pb1b, const void* pb2a, const void* pb2b,
    const void* pWfc, const void* pbfc, const int* __restrict__ flags,
    int* __restrict__ batch32, float* __restrict__ params) {
    int b = blockIdx.x;
    if (b < 49) {
        int i = b * 1024 + threadIdx.x;
        if (i < N_NODES) {
            const int* p = (const int*)braw;
            batch32[i] = flags[1] ? p[2 * i] : p[i];
        }
    } else {
        int i = threadIdx.x;
        const void* srcp;
        int j;
        if (i < 128)      { srcp = pb1a; j = i; }
        else if (i < 256) { srcp = pb1b; j = i - 128; }
        else if (i < 384) { srcp = pb2a; j = i - 256; }
        else if (i < 512) { srcp = pb2b; j = i - 384; }
        else if (i < 768) { srcp = pWfc; j = i - 512; }
        else if (i < 770) { srcp = pbfc; j = i - 768; }
        else return;
        params[i] = flags[0] ? ((const float*)srcp)[j] : bf2f(((const ushort_t*)srcp)[j]);
    }
}

// ---------------- CSR build (counting sort by dst) ----------------

__global__ void zero_int_kernel(int* p, int n) {
    int i = blockIdx.x * 256 + threadIdx.x;
    if (i < n) p[i] = 0;
}

// Two-level scan, stage 1: per-block (256-elem) sums.
__global__ __launch_bounds__(256) void scan_reduce_kernel(const int* __restrict__ cnt,
                                                          int* __restrict__ bsum) {
    __shared__ int buf[256];
    int t = threadIdx.x;
    int i = blockIdx.x * 256 + t;
    buf[t] = (i < N_NODES) ? cnt[i] : 0;
    __syncthreads();
    for (int off = 128; off > 0; off >>= 1) {
        if (t < off) buf[t] += buf[t + off];
        __syncthreads();
    }
    if (t == 0) bsum[blockIdx.x] = buf[0];
}

// Stage 2: single small block scans the SCAN_BLOCKS block sums (exclusive).
__global__ __launch_bounds__(256) void scan_bsum_kernel(int* __restrict__ bsum,
                                                        int* __restrict__ rp) {
    __shared__ int buf[256];
    int t = threadIdx.x;
    int v = (t < SCAN_BLOCKS) ? bsum[t] : 0;
    buf[t] = v;
    __syncthreads();
    for (int off = 1; off < 256; off <<= 1) {
        int x = (t >= off) ? buf[t - off] : 0;
        __syncthreads();
        buf[t] += x;
        __syncthreads();
    }
    if (t < SCAN_BLOCKS) bsum[t] = buf[t] - v;  // exclusive
    if (t == 255) rp[N_NODES] = buf[255];       // total edge count
}

// Stage 3: per-block exclusive rescan + block offset; writes rp and rewrites
// cnt in-place as the running cursor ("cur") for fill_kernel.
__global__ __launch_bounds__(256) void scan_final_kernel(int* __restrict__ cnt,
                                                         const int* __restrict__ bsum,
                                                         int* __restrict__ rp) {
    __shared__ int buf[256];
    int t = threadIdx.x;
    int i = blockIdx.x * 256 + t;
    int v = (i < N_NODES) ? cnt[i] : 0;
    buf[t] = v;
    __syncthreads();
    for (int off = 1; off < 256; off <<= 1) {
        int x = (t >= off) ? buf[t - off] : 0;
        __syncthreads();
        buf[t] += x;
        __syncthreads();
    }
    if (i < N_NODES) {
        int r = bsum[blockIdx.x] + buf[t] - v;  // exclusive prefix
        rp[i] = r;
        cnt[i] = r;
    }
}

__global__ void fill_kernel(const int* __restrict__ src, const int* __restrict__ dst,
                            int* __restrict__ cur, int* __restrict__ csr) {
    int e = blockIdx.x * 256 + threadIdx.x;
    if (e < N_EDGES) {
        int p = atomicAdd(&cur[dst[e]], 1);
        csr[p] = src[e];
    }
}

// ---------------- W -> B-fragment permutation (all 4 weights in one launch) ----
// B-frag for (kstep s, ntile t, lane L): 8 bf16 = W[k=s*32+(L>>4)*8+j][n=t*16+(L&15)]
__global__ void wperm4_kernel(const void* W0, const void* W1, const void* W2, const void* W3,
                              const int* __restrict__ flags, ushort_t* __restrict__ out) {
    int gidx = blockIdx.x * 256 + threadIdx.x;  // 0..65535
    int which = gidx >> 14;
    const void* W = (which == 0) ? W0 : (which == 1) ? W1 : (which == 2) ? W2 : W3;
    int idx = gidx & 16383;
    int j = idx & 7;
    int L = (idx >> 3) & 63;
    int t = (idx >> 9) & 7;
    int s = idx >> 12;
    int k = s * 32 + (L >> 4) * 8 + j;
    int n = t * 16 + (L & 15);
    int off = k * DIM + n;
    out[gidx] = flags[0] ? f2bf(((const float*)W)[off]) : ((const ushort_t*)W)[off];
}

// ---------------- aggregation: h[n] = feat[n] + sum_{j in in-edges} feat[src_j] ----
// Half-wave (32 lanes) per node, uint2 (4 bf16) per lane; edge loop unrolled x4.
// => up to 8 gathers in flight per wave (vs 1 before) to hide L2/HBM latency.
__global__ __launch_bounds__(256) void agg_kernel(const ushort_t* __restrict__ feat,
                                                  const int* __restrict__ rp,
                                                  const int* __restrict__ csr,
                                                  ushort_t* __restrict__ hout) {
    int n = blockIdx.x * 8 + (threadIdx.x >> 5);
    int lane = threadIdx.x & 31;
    if (n >= N_NODES) return;
    const uint2* fp = reinterpret_cast<const uint2*>(feat);  // row = 32 x uint2
    uint2 v = fp[n * 32 + lane];
    float a0 = bf2f((ushort_t)(v.x & 0xffff));
    float a1 = bf2f((ushort_t)(v.x >> 16));
    float a2 = bf2f((ushort_t)(v.y & 0xffff));
    float a3 = bf2f((ushort_t)(v.y >> 16));
    int e0 = rp[n], e1 = rp[n + 1];
    int j = e0;
    for (; j + 4 <= e1; j += 4) {
        int s0 = csr[j], s1 = csr[j + 1], s2 = csr[j + 2], s3 = csr[j + 3];
        uint2 w0 = fp[s0 * 32 + lane];
        uint2 w1 = fp[s1 * 32 + lane];
        uint2 w2 = fp[s2 * 32 + lane];
        uint2 w3 = fp[s3 * 32 + lane];
        a0 += bf2f((ushort_t)(w0.x & 0xffff)); a1 += bf2f((ushort_t)(w0.x >> 16));
        a2 += bf2f((ushort_t)(w0.y & 0xffff)); a3 += bf2f((ushort_t)(w0.y >> 16));
        a0 += bf2f((ushort_t)(w1.x & 0xffff)); a1 += bf2f((ushort_t)(w1.x >> 16));
        a2 += bf2f((ushort_t)(w1.y & 0xffff)); a3 += bf2f((ushort_t)(w1.y >> 16));
        a0 += bf2f((ushort_t)(w2.x & 0xffff)); a1 += bf2f((ushort_t)(w2.x >> 16));
        a2 += bf2f((ushort_t)(w2.y & 0xffff)); a3 += bf2f((ushort_t)(w2.y >> 16));
        a0 += bf2f((ushort_t)(w3.x & 0xffff)); a1 += bf2f((ushort_t)(w3.x >> 16));
        a2 += bf2f((ushort_t)(w3.y & 0xffff)); a3 += bf2f((ushort_t)(w3.y >> 16));
    }
    for (; j < e1; ++j) {
        int s = csr[j];
        uint2 w = fp[s * 32 + lane];
        a0 += bf2f((ushort_t)(w.x & 0xffff)); a1 += bf2f((ushort_t)(w.x >> 16));
        a2 += bf2f((ushort_t)(w.y & 0xffff)); a3 += bf2f((ushort_t)(w.y >> 16));
    }
    uint2 o;
    o.x = (uint_t)f2bf(a0) | ((uint_t)f2bf(a1) << 16);
    o.y = (uint_t)f2bf(a2) | ((uint_t)f2bf(a3) << 16);
    reinterpret_cast<uint2*>(hout)[n * 32 + lane] = o;
}

// ---------------- fused MLP: hout = relu(relu(hin@Wa+ba)@Wb+bb) ----------------
// 64 rows per 256-thread block (4 waves). Safe in-place (stages own rows first).
__global__ __launch_bounds__(256) void mlp_kernel(const ushort_t* __restrict__ hin,
                                                  const ushort_t* __restrict__ wpA,
                                                  const float* __restrict__ ba,
                                                  const ushort_t* __restrict__ wpB,
                                                  const float* __restrict__ bb,
                                                  ushort_t* __restrict__ hout) {
    __shared__ ushort_t As[64 * LDA];
    int tid = threadIdx.x;
    int wave = tid >> 6;
    int lane = tid & 63;
    int quad = lane >> 4;
    int cl = lane & 15;
    int row0 = blockIdx.x * 64;

    bf16x8 B1[2][4], B2[2][4];
#pragma unroll
    for (int ti = 0; ti < 2; ++ti) {
        int t = 2 * wave + ti;
#pragma unroll
        for (int s = 0; s < 4; ++s) {
            B1[ti][s] = as_bf16x8(reinterpret_cast<const uint4*>(wpA)[(s * 8 + t) * 64 + lane]);
            B2[ti][s] = as_bf16x8(reinterpret_cast<const uint4*>(wpB)[(s * 8 + t) * 64 + lane]);
        }
    }

    for (int i = tid; i < 64 * 16; i += 256) {
        int r = i >> 4, c8 = i & 15;
        uint4 v = make_uint4(0u, 0u, 0u, 0u);
        int gr = row0 + r;
        if (gr < N_NODES)
            v = reinterpret_cast<const uint4*>(hin + (size_t)gr * DIM)[c8];
        *reinterpret_cast<uint4*>(&As[r * LDA + c8 * 8]) = v;
    }
    __syncthreads();

    f32x4 acc[4][2];
#pragma unroll
    for (int m = 0; m < 4; ++m)
#pragma unroll
        for (int ti = 0; ti < 2; ++ti)
#pragma unroll
            for (int r = 0; r < 4; ++r) acc[m][ti][r] = 0.f;

#pragma unroll
    for (int s = 0; s < 4; ++s) {
#pragma unroll
        for (int m = 0; m < 4; ++m) {
            bf16x8 a = *reinterpret_cast<const bf16x8*>(&As[(m * 16 + cl) * LDA + s * 32 + quad * 8]);
#pragma unroll
            for (int ti = 0; ti < 2; ++ti)
                acc[m][ti] = __builtin_amdgcn_mfma_f32_16x16x32_bf16(a, B1[ti][s], acc[m][ti], 0, 0, 0);
        }
    }
    __syncthreads();

#pragma unroll
    for (int ti = 0; ti < 2; ++ti) {
        int col = 32 * wave + ti * 16 + cl;
        float bv = ba[col];
#pragma unroll
        for (int m = 0; m < 4; ++m)
#pragma unroll
            for (int r = 0; r < 4; ++r) {
                float v = acc[m][ti][r] + bv;
                As[(m * 16 + quad * 4 + r) * LDA + col] = f2bf(fmaxf(v, 0.f));
            }
    }
    __syncthreads();

#pragma unroll
    for (int m = 0; m < 4; ++m)
#pragma unroll
        for (int ti = 0; ti < 2; ++ti)
#pragma unroll
            for (int r = 0; r < 4; ++r) acc[m][ti][r] = 0.f;

#pragma unroll
    for (int s = 0; s < 4; ++s) {
#pragma unroll
        for (int m = 0; m < 4; ++m) {
            bf16x8 a = *reinterpret_cast<const bf16x8*>(&As[(m * 16 + cl) * LDA + s * 32 + quad * 8]);
#pragma unroll
            for (int ti = 0; ti < 2; ++ti)
                acc[m][ti] = __builtin_amdgcn_mfma_f32_16x16x32_bf16(a, B2[ti][s], acc[m][ti], 0, 0, 0);
        }
    }

#pragma unroll
    for (int ti = 0; ti < 2; ++ti) {
        int col = 32 * wave + ti * 16 + cl;
        float bv = bb[col];
#pragma unroll
        for (int m = 0; m < 4; ++m)
#pragma unroll
            for (int r = 0; r < 4; ++r) {
                int gr = row0 + m * 16 + quad * 4 + r;
                if (gr < N_NODES) {
                    float v = acc[m][ti][r] + bv;
                    hout[(size_t)gr * DIM + col] = f2bf(fmaxf(v, 0.f));
                }
            }
    }
}

// ---------------- mean-pool per graph + FC(128->2) ----------------
__global__ __launch_bounds__(128) void pool_fc_kernel(const ushort_t* __restrict__ h2,
                                                      const int* __restrict__ batch,
                                                      const float* __restrict__ params,
                                                      const int* __restrict__ flags,
                                                      void* __restrict__ out) {
    int g = blockIdx.x;
    int d = threadIdx.x;
    int lo = 0, hi = N_NODES;
    while (lo < hi) { int mid = (lo + hi) >> 1; if (batch[mid] < g) lo = mid + 1; else hi = mid; }
    int start = lo;
    hi = N_NODES;
    while (lo < hi) { int mid = (lo + hi) >> 1; if (batch[mid] < g + 1) lo = mid + 1; else hi = mid; }
    int end = lo;

    float sum = 0.f;
    for (int n = start; n < end; ++n) sum += bf2f(h2[(size_t)n * DIM + d]);
    int c = end - start;
    float mean = sum / (float)(c > 0 ? c : 1);
    float p0 = mean * params[512 + d * 2 + 0];
    float p1 = mean * params[512 + d * 2 + 1];

    __shared__ float r0[128], r1[128];
    r0[d] = p0; r1[d] = p1;
    __syncthreads();
    for (int off = 64; off > 0; off >>= 1) {
        if (d < off) { r0[d] += r0[d + off]; r1[d] += r1[d + off]; }
        __syncthreads();
    }
    if (d == 0) {
        float o0 = r0[0] + params[768];
        float o1 = r1[0] + params[769];
        if (flags[0]) {  // fp32 problem -> fp32 output
            ((float*)out)[g * 2 + 0] = o0;
            ((float*)out)[g * 2 + 1] = o1;
        } else {         // bf16 problem -> bf16 output
            ((ushort_t*)out)[g * 2 + 0] = f2bf(o0);
            ((ushort_t*)out)[g * 2 + 1] = f2bf(o1);
        }
    }
}

extern "C" void kernel_launch(void* const* d_in, const int* in_sizes, int n_in,
                              void* d_out, int out_size, void* d_ws, size_t ws_size,
                              hipStream_t stream) {
    const void* x = d_in[0];
    const void* ei = d_in[1];
    const void* batch = d_in[2];
    const void* W1a = d_in[3];
    const void* b1a = d_in[4];
    const void* W1b = d_in[5];
    const void* b1b = d_in[6];
    const void* W2a = d_in[7];
    const void* b2a = d_in[8];
    const void* W2b = d_in[9];
    const void* b2b = d_in[10];
    const void* Wfc = d_in[11];
    const void* bfc = d_in[12];

    // Workspace layout (~36 MB, all chunks 16B-aligned)
    char* base = (char*)d_ws;
    ushort_t* hX = (ushort_t*)base;   base += (size_t)N_NODES * DIM * 2;   // 12.8 MB (also h2)
    ushort_t* hA = (ushort_t*)base;   base += (size_t)N_NODES * DIM * 2;   // 12.8 MB
    int* src32 = (int*)base;          base += (size_t)N_EDGES * 4;         // 3.2 MB
    int* dst32 = (int*)base;          base += (size_t)N_EDGES * 4;         // 3.2 MB
    int* batch32 = (int*)base;        base += (size_t)N_NODES * 4;         // 0.2 MB
    int* rp = (int*)base;             base += (size_t)(N_NODES + 4) * 4;
    int* cnt = (int*)base;            base += (size_t)N_NODES * 4;
    int* bsum = (int*)base;           base += 256 * 4;
    int* csr = (int*)base;            base += (size_t)N_EDGES * 4;         // 3.2 MB
    ushort_t* wp = (ushort_t*)base;   base += 4 * 16384 * 2;               // wpA1|wpB1|wpA2|wpB2
    float* params = (float*)base;     base += 772 * 4;
    int* flags = (int*)base;          base += 16;

    ushort_t* wpA1 = wp;
    ushort_t* wpB1 = wp + 16384;
    ushort_t* wpA2 = wp + 2 * 16384;
    ushort_t* wpB2 = wp + 3 * 16384;

    // Zero histogram first (independent of detect)
    zero_int_kernel<<<(N_NODES + 255) / 256, 256, 0, stream>>>(cnt, N_NODES);
    // Detect dtypes, canonicalize (hist fused into edge conversion)
    detect_kernel<<<1, 64, 0, stream>>>(x, ei, flags);
    conv_x_kernel<<<(N_NODES * DIM / 4 + 255) / 256, 256, 0, stream>>>(x, flags, hX);
    conv_edges_hist_kernel<<<(N_EDGES + 255) / 256, 256, 0, stream>>>(ei, flags, src32, dst32, cnt);
    conv_batch_params_kernel<<<50, 1024, 0, stream>>>(batch, b1a, b1b, b2a, b2b, Wfc, bfc,
                                                      flags, batch32, params);
    wperm4_kernel<<<256, 256, 0, stream>>>(W1a, W1b, W2a, W2b, flags, wp);

    // CSR build (two-level scan)
    scan_reduce_kernel<<<SCAN_BLOCKS, 256, 0, stream>>>(cnt, bsum);
    scan_bsum_kernel<<<1, 256, 0, stream>>>(bsum, rp);
    scan_final_kernel<<<SCAN_BLOCKS, 256, 0, stream>>>(cnt, bsum, rp);
    fill_kernel<<<(N_EDGES + 255) / 256, 256, 0, stream>>>(src32, dst32, cnt, csr);

    // Layer 1: agg(hX)->hA, mlp in-place on hA
    agg_kernel<<<(N_NODES + 7) / 8, 256, 0, stream>>>(hX, rp, csr, hA);
    mlp_kernel<<<(N_NODES + 63) / 64, 256, 0, stream>>>(hA, wpA1, params + 0, wpB1, params + 128, hA);
    // Layer 2: agg(hA)->hX, mlp in-place on hX
    agg_kernel<<<(N_NODES + 7) / 8, 256, 0, stream>>>(hA, rp, csr, hX);
    mlp_kernel<<<(N_NODES + 63) / 64, 256, 0, stream>>>(hX, wpA2, params + 256, wpB2, params + 384, hX);
    // Pool + FC
    pool_fc_kernel<<<NUM_GRAPHS, 128, 0, stream>>>(hX, batch32, params, flags, d_out);
}

// Round 6
// 327.898 us; speedup vs baseline: 1.6174x; 1.0198x over previous
//
#include <hip/hip_runtime.h>

typedef unsigned short ushort_t;
typedef unsigned int uint_t;

typedef __bf16 bf16x8 __attribute__((ext_vector_type(8)));
typedef float f32x4 __attribute__((ext_vector_type(4)));

#define N_NODES 50000
#define N_EDGES 800000
#define DIM 128
#define NUM_GRAPHS 512
#define LDA 136  // padded LDS row stride in bf16 elems (128+8)
#define SCAN_BLOCKS ((N_NODES + 255) / 256)  // 196

// fill bucketing: 8 dst-range groups (one per XCD via blockIdx&7 heuristic)
#define FILL_GROUPS 8
#define FILL_BUCKET ((N_NODES + FILL_GROUPS - 1) / FILL_GROUPS)  // 6250
#define FILL_CHUNK 2048
#define FILL_CHUNKS ((N_EDGES + FILL_CHUNK - 1) / FILL_CHUNK)    // 391

__device__ __forceinline__ float bf2f(ushort_t u) {
    return __uint_as_float(((uint_t)u) << 16);
}
__device__ __forceinline__ ushort_t f2bf(float f) {
    uint_t u = __float_as_uint(f);
    u = (u + 0x7FFF + ((u >> 16) & 1)) >> 16;  // RNE
    return (ushort_t)u;
}
__device__ __forceinline__ bf16x8 as_bf16x8(uint4 v) {
    return __builtin_bit_cast(bf16x8, v);
}

// ---------------- dtype detection ----------------
// flags[0] = 1 if float arrays are fp32 (else bf16)
// flags[1] = 1 if int arrays are int64 (else int32)
__global__ void detect_kernel(const void* xraw, const void* eiraw, int* flags) {
    if (threadIdx.x == 0 && blockIdx.x == 0) {
        const ushort_t* u = (const ushort_t*)xraw;
        int extreme = 0;
        for (int i = 0; i < 128; ++i) {
            int e = (u[i] >> 7) & 0xFF;
            if (e >= 0xC0) extreme++;  // |x| >= 2^65: impossible for bf16 N(0,1)
        }
        flags[0] = (extreme > 8) ? 1 : 0;
        const int* p = (const int*)eiraw;
        int nonzero = 0;
        for (int i = 1; i < 64; i += 2) nonzero += (p[i] != 0);
        flags[1] = (nonzero == 0) ? 1 : 0;  // all high-halves zero => int64
    }
}

// ---------------- canonicalization ----------------
// 4 elements per thread (float4 -> ushort4, or uint2 passthrough for bf16)
__global__ void conv_x_kernel(const void* xraw, const int* __restrict__ flags,
                              ushort_t* __restrict__ out) {
    int i = blockIdx.x * 256 + threadIdx.x;
    if (i >= N_NODES * DIM / 4) return;
    if (flags[0]) {
        float4 v = ((const float4*)xraw)[i];
        ushort4 o;
        o.x = f2bf(v.x); o.y = f2bf(v.y); o.z = f2bf(v.z); o.w = f2bf(v.w);
        ((ushort4*)out)[i] = o;
    } else {
        ((uint2*)out)[i] = ((const uint2*)xraw)[i];
    }
}

// edges -> int32 src/dst + histogram of dst (cnt must be pre-zeroed)
__global__ void conv_edges_hist_kernel(const void* eiraw, const int* __restrict__ flags,
                                       int* __restrict__ src, int* __restrict__ dsto,
                                       int* __restrict__ cnt) {
    int e = blockIdx.x * 256 + threadIdx.x;
    if (e >= N_EDGES) return;
    const int* p = (const int*)eiraw;
    int s, d;
    if (flags[1]) {  // int64: take low halves (little-endian)
        s = p[2 * e];
        d = p[2 * (N_EDGES + e)];
    } else {
        s = p[e];
        d = p[N_EDGES + e];
    }
    src[e] = s;
    dsto[e] = d;
    atomicAdd(&cnt[d], 1);
}

// blocks 0..48: batch -> int32.  block 49: params.
// canonical fp32 params: [0:128)=b1a [128:256)=b1b [256:384)=b2a [384:512)=b2b
//                        [512:768)=Wfc(row-major 128x2) [768:770)=bfc
__global__ __launch_bounds__(1024) void conv_batch_params_kernel(
    const void* braw,
    const void* pb1a, const void* pb1b, const void* pb2a, const void* pb2b,
    const void* pWfc, const void* pbfc, const int* __restrict__ flags,
    int* __restrict__ batch32, float* __restrict__ params) {
    int b = blockIdx.x;
    if (b < 49) {
        int i = b * 1024 + threadIdx.x;
        if (i < N_NODES) {
            const int* p = (const int*)braw;
            batch32[i] = flags[1] ? p[2 * i] : p[i];
        }
    } else {
        int i = threadIdx.x;
        const void* srcp;
        int j;
        if (i < 128)      { srcp = pb1a; j = i; }
        else if (i < 256) { srcp = pb1b; j = i - 128; }
        else if (i < 384) { srcp = pb2a; j = i - 256; }
        else if (i < 512) { srcp = pb2b; j = i - 384; }
        else if (i < 768) { srcp = pWfc; j = i - 512; }
        else if (i < 770) { srcp = pbfc; j = i - 768; }
        else return;
        params[i] = flags[0] ? ((const float*)srcp)[j] : bf2f(((const ushort_t*)srcp)[j]);
    }
}

// ---------------- CSR build (counting sort by dst) ----------------

__global__ void zero_int_kernel(int* p, int n) {
    int i = blockIdx.x * 256 + threadIdx.x;
    if (i < n) p[i] = 0;
}

// Two-level scan, stage 1: per-block (256-elem) sums.
__global__ __launch_bounds__(256) void scan_reduce_kernel(const int* __restrict__ cnt,
                                                          int* __restrict__ bsum) {
    __shared__ int buf[256];
    int t = threadIdx.x;
    int i = blockIdx.x * 256 + t;
    buf[t] = (i < N_NODES) ? cnt[i] : 0;
    __syncthreads();
    for (int off = 128; off > 0; off >>= 1) {
        if (t < off) buf[t] += buf[t + off];
        __syncthreads();
    }
    if (t == 0) bsum[blockIdx.x] = buf[0];
}

// Stage 2: single small block scans the SCAN_BLOCKS block sums (exclusive).
__global__ __launch_bounds__(256) void scan_bsum_kernel(int* __restrict__ bsum,
                                                        int* __restrict__ rp) {
    __shared__ int buf[256];
    int t = threadIdx.x;
    int v = (t < SCAN_BLOCKS) ? bsum[t] : 0;
    buf[t] = v;
    __syncthreads();
    for (int off = 1; off < 256; off <<= 1) {
        int x = (t >= off) ? buf[t - off] : 0;
        __syncthreads();
        buf[t] += x;
        __syncthreads();
    }
    if (t < SCAN_BLOCKS) bsum[t] = buf[t] - v;  // exclusive
    if (t == 255) rp[N_NODES] = buf[255];       // total edge count
}

// Stage 3: per-block exclusive rescan + block offset; writes rp and rewrites
// cnt in-place as the running cursor ("cur") for fill_kernel.
__global__ __launch_bounds__(256) void scan_final_kernel(int* __restrict__ cnt,
                                                         const int* __restrict__ bsum,
                                                         int* __restrict__ rp) {
    __shared__ int buf[256];
    int t = threadIdx.x;
    int i = blockIdx.x * 256 + t;
    int v = (i < N_NODES) ? cnt[i] : 0;
    buf[t] = v;
    __syncthreads();
    for (int off = 1; off < 256; off <<= 1) {
        int x = (t >= off) ? buf[t - off] : 0;
        __syncthreads();
        buf[t] += x;
        __syncthreads();
    }
    if (i < N_NODES) {
        int r = bsum[blockIdx.x] + buf[t] - v;  // exclusive prefix
        rp[i] = r;
        cnt[i] = r;
    }
}

// Bucketed CSR fill: group = blockIdx&7 -> one dst-range bucket per XCD
// (blockIdx%8 ~ XCD round-robin heuristic). Bucket g's csr region (~0.4 MB)
// is then written by only one XCD's L2 -> full-line writebacks instead of
// the 51 MB of partial-line cross-XCD writebacks measured in R5.
__global__ __launch_bounds__(256) void fill_kernel(const int* __restrict__ src,
                                                   const int* __restrict__ dst,
                                                   int* __restrict__ cur,
                                                   int* __restrict__ csr) {
    int group = blockIdx.x & (FILL_GROUPS - 1);
    int chunk = blockIdx.x >> 3;
    int base = chunk * FILL_CHUNK;
    int lo = group * FILL_BUCKET;
    int hi = lo + FILL_BUCKET;
#pragma unroll
    for (int i = 0; i < FILL_CHUNK; i += 256) {
        int e = base + i + threadIdx.x;
        if (e < N_EDGES) {
            int d = dst[e];
            if (d >= lo && d < hi) {
                int p = atomicAdd(&cur[d], 1);
                csr[p] = src[e];
            }
        }
    }
}

// ---------------- W -> B-fragment permutation (all 4 weights in one launch) ----
// B-frag for (kstep s, ntile t, lane L): 8 bf16 = W[k=s*32+(L>>4)*8+j][n=t*16+(L&15)]
__global__ void wperm4_kernel(const void* W0, const void* W1, const void* W2, const void* W3,
                              const int* __restrict__ flags, ushort_t* __restrict__ out) {
    int gidx = blockIdx.x * 256 + threadIdx.x;  // 0..65535
    int which = gidx >> 14;
    const void* W = (which == 0) ? W0 : (which == 1) ? W1 : (which == 2) ? W2 : W3;
    int idx = gidx & 16383;
    int j = idx & 7;
    int L = (idx >> 3) & 63;
    int t = (idx >> 9) & 7;
    int s = idx >> 12;
    int k = s * 32 + (L >> 4) * 8 + j;
    int n = t * 16 + (L & 15);
    int off = k * DIM + n;
    out[gidx] = flags[0] ? f2bf(((const float*)W)[off]) : ((const ushort_t*)W)[off];
}

// ---------------- aggregation: h[n] = feat[n] + sum_{j in in-edges} feat[src_j] ----
// Half-wave (32 lanes) per node, uint2 (4 bf16) per lane; edge loop unrolled x4.
__global__ __launch_bounds__(256) void agg_kernel(const ushort_t* __restrict__ feat,
                                                  const int* __restrict__ rp,
                                                  const int* __restrict__ csr,
                                                  ushort_t* __restrict__ hout) {
    int n = blockIdx.x * 8 + (threadIdx.x >> 5);
    int lane = threadIdx.x & 31;
    if (n >= N_NODES) return;
    const uint2* fp = reinterpret_cast<const uint2*>(feat);  // row = 32 x uint2
    uint2 v = fp[n * 32 + lane];
    float a0 = bf2f((ushort_t)(v.x & 0xffff));
    float a1 = bf2f((ushort_t)(v.x >> 16));
    float a2 = bf2f((ushort_t)(v.y & 0xffff));
    float a3 = bf2f((ushort_t)(v.y >> 16));
    int e0 = rp[n], e1 = rp[n + 1];
    int j = e0;
    for (; j + 4 <= e1; j += 4) {
        int s0 = csr[j], s1 = csr[j + 1], s2 = csr[j + 2], s3 = csr[j + 3];
        uint2 w0 = fp[s0 * 32 + lane];
        uint2 w1 = fp[s1 * 32 + lane];
        uint2 w2 = fp[s2 * 32 + lane];
        uint2 w3 = fp[s3 * 32 + lane];
        a0 += bf2f((ushort_t)(w0.x & 0xffff)); a1 += bf2f((ushort_t)(w0.x >> 16));
        a2 += bf2f((ushort_t)(w0.y & 0xffff)); a3 += bf2f((ushort_t)(w0.y >> 16));
        a0 += bf2f((ushort_t)(w1.x & 0xffff)); a1 += bf2f((ushort_t)(w1.x >> 16));
        a2 += bf2f((ushort_t)(w1.y & 0xffff)); a3 += bf2f((ushort_t)(w1.y >> 16));
        a0 += bf2f((ushort_t)(w2.x & 0xffff)); a1 += bf2f((ushort_t)(w2.x >> 16));
        a2 += bf2f((ushort_t)(w2.y & 0xffff)); a3 += bf2f((ushort_t)(w2.y >> 16));
        a0 += bf2f((ushort_t)(w3.x & 0xffff)); a1 += bf2f((ushort_t)(w3.x >> 16));
        a2 += bf2f((ushort_t)(w3.y & 0xffff)); a3 += bf2f((ushort_t)(w3.y >> 16));
    }
    for (; j < e1; ++j) {
        int s = csr[j];
        uint2 w = fp[s * 32 + lane];
        a0 += bf2f((ushort_t)(w.x & 0xffff)); a1 += bf2f((ushort_t)(w.x >> 16));
        a2 += bf2f((ushort_t)(w.y & 0xffff)); a3 += bf2f((ushort_t)(w.y >> 16));
    }
    uint2 o;
    o.x = (uint_t)f2bf(a0) | ((uint_t)f2bf(a1) << 16);
    o.y = (uint_t)f2bf(a2) | ((uint_t)f2bf(a3) << 16);
    reinterpret_cast<uint2*>(hout)[n * 32 + lane] = o;
}

// ---------------- fused MLP: hout = relu(relu(hin@Wa+ba)@Wb+bb) ----------------
// 64 rows per 256-thread block (4 waves). Safe in-place (stages own rows first).
__global__ __launch_bounds__(256) void mlp_kernel(const ushort_t* __restrict__ hin,
                                                  const ushort_t* __restrict__ wpA,
                                                  const float* __restrict__ ba,
                                                  const ushort_t* __restrict__ wpB,
                                                  const float* __restrict__ bb,
                                                  ushort_t* __restrict__ hout) {
    __shared__ ushort_t As[64 * LDA];
    int tid = threadIdx.x;
    int wave = tid >> 6;
    int lane = tid & 63;
    int quad = lane >> 4;
    int cl = lane & 15;
    int row0 = blockIdx.x * 64;

    bf16x8 B1[2][4], B2[2][4];
#pragma unroll
    for (int ti = 0; ti < 2; ++ti) {
        int t = 2 * wave + ti;
#pragma unroll
        for (int s = 0; s < 4; ++s) {
            B1[ti][s] = as_bf16x8(reinterpret_cast<const uint4*>(wpA)[(s * 8 + t) * 64 + lane]);
            B2[ti][s] = as_bf16x8(reinterpret_cast<const uint4*>(wpB)[(s * 8 + t) * 64 + lane]);
        }
    }

    for (int i = tid; i < 64 * 16; i += 256) {
        int r = i >> 4, c8 = i & 15;
        uint4 v = make_uint4(0u, 0u, 0u, 0u);
        int gr = row0 + r;
        if (gr < N_NODES)
            v = reinterpret_cast<const uint4*>(hin + (size_t)gr * DIM)[c8];
        *reinterpret_cast<uint4*>(&As[r * LDA + c8 * 8]) = v;
    }
    __syncthreads();

    f32x4 acc[4][2];
#pragma unroll
    for (int m = 0; m < 4; ++m)
#pragma unroll
        for (int ti = 0; ti < 2; ++ti)
#pragma unroll
            for (int r = 0; r < 4; ++r) acc[m][ti][r] = 0.f;

#pragma unroll
    for (int s = 0; s < 4; ++s) {
#pragma unroll
        for (int m = 0; m < 4; ++m) {
            bf16x8 a = *reinterpret_cast<const bf16x8*>(&As[(m * 16 + cl) * LDA + s * 32 + quad * 8]);
#pragma unroll
            for (int ti = 0; ti < 2; ++ti)
                acc[m][ti] = __builtin_amdgcn_mfma_f32_16x16x32_bf16(a, B1[ti][s], acc[m][ti], 0, 0, 0);
        }
    }
    __syncthreads();

#pragma unroll
    for (int ti = 0; ti < 2; ++ti) {
        int col = 32 * wave + ti * 16 + cl;
        float bv = ba[col];
#pragma unroll
        for (int m = 0; m < 4; ++m)
#pragma unroll
            for (int r = 0; r < 4; ++r) {
                float v = acc[m][ti][r] + bv;
                As[(m * 16 + quad * 4 + r) * LDA + col] = f2bf(fmaxf(v, 0.f));
            }
    }
    __syncthreads();

#pragma unroll
    for (int m = 0; m < 4; ++m)
#pragma unroll
        for (int ti = 0; ti < 2; ++ti)
#pragma unroll
            for (int r = 0; r < 4; ++r) acc[m][ti][r] = 0.f;

#pragma unroll
    for (int s = 0; s < 4; ++s) {
#pragma unroll
        for (int m = 0; m < 4; ++m) {
            bf16x8 a = *reinterpret_cast<const bf16x8*>(&As[(m * 16 + cl) * LDA + s * 32 + quad * 8]);
#pragma unroll
            for (int ti = 0; ti < 2; ++ti)
                acc[m][ti] = __builtin_amdgcn_mfma_f32_16x16x32_bf16(a, B2[ti][s], acc[m][ti], 0, 0, 0);
        }
    }

#pragma unroll
    for (int ti = 0; ti < 2; ++ti) {
        int col = 32 * wave + ti * 16 + cl;
        float bv = bb[col];
#pragma unroll
        for (int m = 0; m < 4; ++m)
#pragma unroll
            for (int r = 0; r < 4; ++r) {
                int gr = row0 + m * 16 + quad * 4 + r;
                if (gr < N_NODES) {
                    float v = acc[m][ti][r] + bv;
                    hout[(size_t)gr * DIM + col] = f2bf(fmaxf(v, 0.f));
                }
            }
    }
}

// ---------------- mean-pool per graph + FC(128->2) ----------------
__global__ __launch_bounds__(128) void pool_fc_kernel(const ushort_t* __restrict__ h2,
                                                      const int* __restrict__ batch,
                                                      const float* __restrict__ params,
                                                      const int* __restrict__ flags,
                                                      void* __restrict__ out) {
    int g = blockIdx.x;
    int d = threadIdx.x;
    int lo = 0, hi = N_NODES;
    while (lo < hi) { int mid = (lo + hi) >> 1; if (batch[mid] < g) lo = mid + 1; else hi = mid; }
    int start = lo;
    hi = N_NODES;
    while (lo < hi) { int mid = (lo + hi) >> 1; if (batch[mid] < g + 1) lo = mid + 1; else hi = mid; }
    int end = lo;

    float sum = 0.f;
    for (int n = start; n < end; ++n) sum += bf2f(h2[(size_t)n * DIM + d]);
    int c = end - start;
    float mean = sum / (float)(c > 0 ? c : 1);
    float p0 = mean * params[512 + d * 2 + 0];
    float p1 = mean * params[512 + d * 2 + 1];

    __shared__ float r0[128], r1[128];
    r0[d] = p0; r1[d] = p1;
    __syncthreads();
    for (int off = 64; off > 0; off >>= 1) {
        if (d < off) { r0[d] += r0[d + off]; r1[d] += r1[d + off]; }
        __syncthreads();
    }
    if (d == 0) {
        float o0 = r0[0] + params[768];
        float o1 = r1[0] + params[769];
        if (flags[0]) {  // fp32 problem -> fp32 output
            ((float*)out)[g * 2 + 0] = o0;
            ((float*)out)[g * 2 + 1] = o1;
        } else {         // bf16 problem -> bf16 output
            ((ushort_t*)out)[g * 2 + 0] = f2bf(o0);
            ((ushort_t*)out)[g * 2 + 1] = f2bf(o1);
        }
    }
}

extern "C" void kernel_launch(void* const* d_in, const int* in_sizes, int n_in,
                              void* d_out, int out_size, void* d_ws, size_t ws_size,
                              hipStream_t stream) {
    const void* x = d_in[0];
    const void* ei = d_in[1];
    const void* batch = d_in[2];
    const void* W1a = d_in[3];
    const void* b1a = d_in[4];
    const void* W1b = d_in[5];
    const void* b1b = d_in[6];
    const void* W2a = d_in[7];
    const void* b2a = d_in[8];
    const void* W2b = d_in[9];
    const void* b2b = d_in[10];
    const void* Wfc = d_in[11];
    const void* bfc = d_in[12];

    // Workspace layout (~36 MB, all chunks 16B-aligned)
    char* base = (char*)d_ws;
    ushort_t* hX = (ushort_t*)base;   base += (size_t)N_NODES * DIM * 2;   // 12.8 MB (also h2)
    ushort_t* hA = (ushort_t*)base;   base += (size_t)N_NODES * DIM * 2;   // 12.8 MB
    int* src32 = (int*)base;          base += (size_t)N_EDGES * 4;         // 3.2 MB
    int* dst32 = (int*)base;          base += (size_t)N_EDGES * 4;         // 3.2 MB
    int* batch32 = (int*)base;        base += (size_t)N_NODES * 4;         // 0.2 MB
    int* rp = (int*)base;             base += (size_t)(N_NODES + 4) * 4;
    int* cnt = (int*)base;            base += (size_t)N_NODES * 4;
    int* bsum = (int*)base;           base += 256 * 4;
    int* csr = (int*)base;            base += (size_t)N_EDGES * 4;         // 3.2 MB
    ushort_t* wp = (ushort_t*)base;   base += 4 * 16384 * 2;               // wpA1|wpB1|wpA2|wpB2
    float* params = (float*)base;     base += 772 * 4;
    int* flags = (int*)base;          base += 16;

    ushort_t* wpA1 = wp;
    ushort_t* wpB1 = wp + 16384;
    ushort_t* wpA2 = wp + 2 * 16384;
    ushort_t* wpB2 = wp + 3 * 16384;

    // Zero histogram first (independent of detect)
    zero_int_kernel<<<(N_NODES + 255) / 256, 256, 0, stream>>>(cnt, N_NODES);
    // Detect dtypes, canonicalize (hist fused into edge conversion)
    detect_kernel<<<1, 64, 0, stream>>>(x, ei, flags);
    conv_x_kernel<<<(N_NODES * DIM / 4 + 255) / 256, 256, 0, stream>>>(x, flags, hX);
    conv_edges_hist_kernel<<<(N_EDGES + 255) / 256, 256, 0, stream>>>(ei, flags, src32, dst32, cnt);
    conv_batch_params_kernel<<<50, 1024, 0, stream>>>(batch, b1a, b1b, b2a, b2b, Wfc, bfc,
                                                      flags, batch32, params);
    wperm4_kernel<<<256, 256, 0, stream>>>(W1a, W1b, W2a, W2b, flags, wp);

    // CSR build (two-level scan + XCD-bucketed fill)
    scan_reduce_kernel<<<SCAN_BLOCKS, 256, 0, stream>>>(cnt, bsum);
    scan_bsum_kernel<<<1, 256, 0, stream>>>(bsum, rp);
    scan_final_kernel<<<SCAN_BLOCKS, 256, 0, stream>>>(cnt, bsum, rp);
    fill_kernel<<<FILL_CHUNKS * FILL_GROUPS, 256, 0, stream>>>(src32, dst32, cnt, csr);

    // Layer 1: agg(hX)->hA, mlp in-place on hA
    agg_kernel<<<(N_NODES + 7) / 8, 256, 0, stream>>>(hX, rp, csr, hA);
    mlp_kernel<<<(N_NODES + 63) / 64, 256, 0, stream>>>(hA, wpA1, params + 0, wpB1, params + 128, hA);
    // Layer 2: agg(hA)->hX, mlp in-place on hX
    agg_kernel<<<(N_NODES + 7) / 8, 256, 0, stream>>>(hA, rp, csr, hX);
    mlp_kernel<<<(N_NODES + 63) / 64, 256, 0, stream>>>(hX, wpA2, params + 256, wpB2, params + 384, hX);
    // Pool + FC
    pool_fc_kernel<<<NUM_GRAPHS, 128, 0, stream>>>(hX, batch32, params, flags, d_out);
}